// Round 2
// baseline (433.553 us; speedup 1.0000x reference)
//
#include <hip/hip_runtime.h>

typedef __bf16 bf16;
typedef __bf16 bf16x8 __attribute__((ext_vector_type(8)));
typedef __bf16 bf16x4 __attribute__((ext_vector_type(4)));
typedef float  f32x4  __attribute__((ext_vector_type(4)));

#define BATCH 65536
#define NCAT  608   // 599 spline logits + a + b, padded to 608

// ---------------------------------------------------------------------------
// Kernel 0: cast weights to bf16; assemble Wcat[608][512] = [WV; Wa; Wb; 0]
// ---------------------------------------------------------------------------
__global__ __launch_bounds__(256) void prep_kernel(
    const float* W1, const float* W2, const float* WV,
    const float* bV, const float* Wa, const float* ba,
    const float* Wb, const float* bb,
    bf16* w1b, bf16* w2b, bf16* wcat, float* bcat)
{
    int idx = blockIdx.x * 256 + threadIdx.x;
    const int n1 = 512 * 128, n2 = 512 * 512, n3 = NCAT * 512;
    if (idx < n1) { w1b[idx] = (bf16)W1[idx]; return; }
    idx -= n1;
    if (idx < n2) { w2b[idx] = (bf16)W2[idx]; return; }
    idx -= n2;
    if (idx < n3) {
        int n = idx >> 9, k = idx & 511;
        float v = 0.f;
        if (n < 599)       v = WV[n * 512 + k];
        else if (n == 599) v = Wa[k];
        else if (n == 600) v = Wb[k];
        wcat[idx] = (bf16)v;
        return;
    }
    idx -= n3;
    if (idx < NCAT) {
        float v = 0.f;
        if (idx < 599)       v = bV[idx];
        else if (idx == 599) v = ba[0];
        else if (idx == 600) v = bb[0];
        bcat[idx] = v;
    }
}

// ---------------------------------------------------------------------------
// Kernel 1: fused MLP.  Per 64-row block:
//   X1 = relu(LN(inputs @ W1^T + b1)) kept in LDS (never hits HBM),
//   X2 = relu(LN(X1 @ W2^T + b2))     -> global bf16 (coalesced via LDS copy).
// 8 waves as 2(M) x 4(N); wave tile 32x128; mfma_f32_16x16x32_bf16.
// ---------------------------------------------------------------------------
__global__ __launch_bounds__(512) void fused_mlp(
    const float* __restrict__ inputs,
    const bf16* __restrict__ w1, const float* __restrict__ b1,
    const float* __restrict__ g1, const float* __restrict__ be1,
    const bf16* __restrict__ w2, const float* __restrict__ b2,
    const float* __restrict__ g2, const float* __restrict__ be2,
    bf16* __restrict__ x2)
{
    __shared__ bf16 As[64][136];     // input tile (bf16), staged once
    __shared__ bf16 Bs[512][40];     // weight K-slice
    __shared__ bf16 Xs[64][520];     // X1 (phase 2 A-source), then X2 staging
    __shared__ float Psum[64][4];
    __shared__ float Psq[64][4];

    const int t    = threadIdx.x;
    const int lane = t & 63, wid = t >> 6;
    const int wm = wid >> 2, wn = wid & 3;       // 2 x 4 wave grid
    const int l16 = lane & 15, g16 = lane >> 4;
    const long row0 = (long)blockIdx.x * 64;

    // ---- stage input tile 64x128 f32 -> bf16 (once) ----
    {
        const int r = t >> 3, c0 = (t & 7) * 16;
        const float* src = &inputs[(row0 + r) * 128 + c0];
        float4 v0 = *(const float4*)(src);
        float4 v1 = *(const float4*)(src + 4);
        float4 v2 = *(const float4*)(src + 8);
        float4 v3 = *(const float4*)(src + 12);
        bf16x8 h0, h1;
        h0[0]=(bf16)v0.x; h0[1]=(bf16)v0.y; h0[2]=(bf16)v0.z; h0[3]=(bf16)v0.w;
        h0[4]=(bf16)v1.x; h0[5]=(bf16)v1.y; h0[6]=(bf16)v1.z; h0[7]=(bf16)v1.w;
        h1[0]=(bf16)v2.x; h1[1]=(bf16)v2.y; h1[2]=(bf16)v2.z; h1[3]=(bf16)v2.w;
        h1[4]=(bf16)v3.x; h1[5]=(bf16)v3.y; h1[6]=(bf16)v3.z; h1[7]=(bf16)v3.w;
        *(bf16x8*)&As[r][c0]     = h0;
        *(bf16x8*)&As[r][c0 + 8] = h1;
    }

    f32x4 acc[2][8];
#pragma unroll
    for (int a = 0; a < 2; ++a)
#pragma unroll
        for (int b = 0; b < 8; ++b) acc[a][b] = (f32x4){0.f, 0.f, 0.f, 0.f};

    // ================= phase 1: X1 = inputs @ W1^T (K=128) =================
    for (int k0 = 0; k0 < 128; k0 += 32) {
        __syncthreads();
        {
            const bf16* wr = &w1[t * 128 + k0];
            *(bf16x8*)&Bs[t][0]  = *(const bf16x8*)&wr[0];
            *(bf16x8*)&Bs[t][8]  = *(const bf16x8*)&wr[8];
            *(bf16x8*)&Bs[t][16] = *(const bf16x8*)&wr[16];
            *(bf16x8*)&Bs[t][24] = *(const bf16x8*)&wr[24];
        }
        __syncthreads();
        bf16x8 af0 = *(const bf16x8*)&As[wm * 32 + l16][k0 + g16 * 8];
        bf16x8 af1 = *(const bf16x8*)&As[wm * 32 + 16 + l16][k0 + g16 * 8];
#pragma unroll
        for (int fn = 0; fn < 8; ++fn) {
            bf16x8 bv = *(const bf16x8*)&Bs[wn * 128 + fn * 16 + l16][g16 * 8];
            acc[0][fn] = __builtin_amdgcn_mfma_f32_16x16x32_bf16(af0, bv, acc[0][fn], 0, 0, 0);
            acc[1][fn] = __builtin_amdgcn_mfma_f32_16x16x32_bf16(af1, bv, acc[1][fn], 0, 0, 0);
        }
    }

    // ---- epilogue 1: +b1, LN, ReLU -> Xs (LDS only) ----
#pragma unroll
    for (int fm = 0; fm < 2; ++fm)
#pragma unroll
        for (int fn = 0; fn < 8; ++fn) {
            float bv = b1[wn * 128 + fn * 16 + l16];
#pragma unroll
            for (int i = 0; i < 4; ++i) acc[fm][fn][i] += bv;
        }
#pragma unroll
    for (int fm = 0; fm < 2; ++fm)
#pragma unroll
        for (int i = 0; i < 4; ++i) {
            float s = 0.f, q = 0.f;
#pragma unroll
            for (int fn = 0; fn < 8; ++fn) { float v = acc[fm][fn][i]; s += v; q += v * v; }
#pragma unroll
            for (int m = 1; m < 16; m <<= 1) { s += __shfl_xor(s, m); q += __shfl_xor(q, m); }
            if (l16 == 0) {
                int lr = wm * 32 + fm * 16 + g16 * 4 + i;
                Psum[lr][wn] = s; Psq[lr][wn] = q;
            }
        }
    __syncthreads();
#pragma unroll
    for (int fm = 0; fm < 2; ++fm)
#pragma unroll
        for (int i = 0; i < 4; ++i) {
            int lr = wm * 32 + fm * 16 + g16 * 4 + i;
            float s = Psum[lr][0] + Psum[lr][1] + Psum[lr][2] + Psum[lr][3];
            float q = Psq[lr][0] + Psq[lr][1] + Psq[lr][2] + Psq[lr][3];
            float mean = s * (1.f / 512.f);
            float var  = q * (1.f / 512.f) - mean * mean;
            float rstd = rsqrtf(var + 1e-5f);
#pragma unroll
            for (int fn = 0; fn < 8; ++fn) {
                int col = wn * 128 + fn * 16 + l16;
                float o = (acc[fm][fn][i] - mean) * rstd * g1[col] + be1[col];
                Xs[lr][col] = (bf16)fmaxf(o, 0.f);
            }
        }

    // ================= phase 2: X2 = X1 @ W2^T (K=512) =================
#pragma unroll
    for (int a = 0; a < 2; ++a)
#pragma unroll
        for (int b = 0; b < 8; ++b) acc[a][b] = (f32x4){0.f, 0.f, 0.f, 0.f};

    for (int k0 = 0; k0 < 512; k0 += 32) {
        __syncthreads();   // first iter: Xs writes visible; later: Bs reuse safe
        {
            const bf16* wr = &w2[t * 512 + k0];
            *(bf16x8*)&Bs[t][0]  = *(const bf16x8*)&wr[0];
            *(bf16x8*)&Bs[t][8]  = *(const bf16x8*)&wr[8];
            *(bf16x8*)&Bs[t][16] = *(const bf16x8*)&wr[16];
            *(bf16x8*)&Bs[t][24] = *(const bf16x8*)&wr[24];
        }
        __syncthreads();
        bf16x8 af0 = *(const bf16x8*)&Xs[wm * 32 + l16][k0 + g16 * 8];
        bf16x8 af1 = *(const bf16x8*)&Xs[wm * 32 + 16 + l16][k0 + g16 * 8];
#pragma unroll
        for (int fn = 0; fn < 8; ++fn) {
            bf16x8 bv = *(const bf16x8*)&Bs[wn * 128 + fn * 16 + l16][g16 * 8];
            acc[0][fn] = __builtin_amdgcn_mfma_f32_16x16x32_bf16(af0, bv, acc[0][fn], 0, 0, 0);
            acc[1][fn] = __builtin_amdgcn_mfma_f32_16x16x32_bf16(af1, bv, acc[1][fn], 0, 0, 0);
        }
    }

    // ---- epilogue 2: +b2, LN, ReLU -> Xs, then coalesced copy to global ----
    __syncthreads();   // all waves done reading Xs (X1); safe to overwrite
#pragma unroll
    for (int fm = 0; fm < 2; ++fm)
#pragma unroll
        for (int fn = 0; fn < 8; ++fn) {
            float bv = b2[wn * 128 + fn * 16 + l16];
#pragma unroll
            for (int i = 0; i < 4; ++i) acc[fm][fn][i] += bv;
        }
#pragma unroll
    for (int fm = 0; fm < 2; ++fm)
#pragma unroll
        for (int i = 0; i < 4; ++i) {
            float s = 0.f, q = 0.f;
#pragma unroll
            for (int fn = 0; fn < 8; ++fn) { float v = acc[fm][fn][i]; s += v; q += v * v; }
#pragma unroll
            for (int m = 1; m < 16; m <<= 1) { s += __shfl_xor(s, m); q += __shfl_xor(q, m); }
            if (l16 == 0) {
                int lr = wm * 32 + fm * 16 + g16 * 4 + i;
                Psum[lr][wn] = s; Psq[lr][wn] = q;
            }
        }
    __syncthreads();
#pragma unroll
    for (int fm = 0; fm < 2; ++fm)
#pragma unroll
        for (int i = 0; i < 4; ++i) {
            int lr = wm * 32 + fm * 16 + g16 * 4 + i;
            float s = Psum[lr][0] + Psum[lr][1] + Psum[lr][2] + Psum[lr][3];
            float q = Psq[lr][0] + Psq[lr][1] + Psq[lr][2] + Psq[lr][3];
            float mean = s * (1.f / 512.f);
            float var  = q * (1.f / 512.f) - mean * mean;
            float rstd = rsqrtf(var + 1e-5f);
#pragma unroll
            for (int fn = 0; fn < 8; ++fn) {
                int col = wn * 128 + fn * 16 + l16;
                float o = (acc[fm][fn][i] - mean) * rstd * g2[col] + be2[col];
                Xs[lr][col] = (bf16)fmaxf(o, 0.f);
            }
        }
    __syncthreads();
#pragma unroll
    for (int i = 0; i < 8; ++i) {     // 4096 chunks of 8 bf16 / 512 threads
        int c  = i * 512 + t;
        int rr = c >> 6;
        int cc = (c & 63) * 8;
        bf16x8 v = *(const bf16x8*)&Xs[rr][cc];
        *(bf16x8*)&x2[(row0 + rr) * 512 + cc] = v;
    }
}

// ---------------------------------------------------------------------------
// Kernel 2: fused sp-GEMM + spline.  Per 64-row block:
//   sp = X2 @ Wcat^T + bcat  -> LDS (bf16), a/b -> LDS f32
//   then register-only spline: each lane OWNS 4 bins; bin params live in regs
//   after the wave scans; output ranges computed by scatter (no search).
// GEMM: 8 waves as 4(M) x 2(N); wave tile 16 x 304 (19 N-frags).
// ---------------------------------------------------------------------------
__global__ __launch_bounds__(512) void gemm_spline(
    const bf16* __restrict__ A, const bf16* __restrict__ W,
    const float* __restrict__ bcat, float* __restrict__ out)
{
    __shared__ bf16 AsB[64][40];
    __shared__ bf16 BsB[NCAT][40];
    __shared__ bf16 spS[64][NCAT];
    __shared__ float abS[64][2];

    const int t    = threadIdx.x;
    const int lane = t & 63, wid = t >> 6;
    const int wm = wid >> 1, wn = wid & 1;       // 4 x 2 wave grid
    const int l16 = lane & 15, g16 = lane >> 4;
    const long row0 = (long)blockIdx.x * 64;

    f32x4 acc[19];
#pragma unroll
    for (int i = 0; i < 19; ++i) acc[i] = (f32x4){0.f, 0.f, 0.f, 0.f};

    const int ar = t >> 3, ac = (t & 7) * 4;

    for (int k0 = 0; k0 < 512; k0 += 32) {
        __syncthreads();
        *(bf16x4*)&AsB[ar][ac] = *(const bf16x4*)&A[(row0 + ar) * 512 + k0 + ac];
        for (int r = t; r < NCAT; r += 512) {
            const bf16* wr = &W[(long)r * 512 + k0];
            *(bf16x8*)&BsB[r][0]  = *(const bf16x8*)&wr[0];
            *(bf16x8*)&BsB[r][8]  = *(const bf16x8*)&wr[8];
            *(bf16x8*)&BsB[r][16] = *(const bf16x8*)&wr[16];
            *(bf16x8*)&BsB[r][24] = *(const bf16x8*)&wr[24];
        }
        __syncthreads();
        bf16x8 af = *(const bf16x8*)&AsB[wm * 16 + l16][g16 * 8];
#pragma unroll
        for (int fn = 0; fn < 19; ++fn) {
            bf16x8 bv = *(const bf16x8*)&BsB[wn * 304 + fn * 16 + l16][g16 * 8];
            acc[fn] = __builtin_amdgcn_mfma_f32_16x16x32_bf16(af, bv, acc[fn], 0, 0, 0);
        }
    }

    // ---- epilogue: +bcat -> spS (bf16) / abS (f32) ----
#pragma unroll
    for (int fn = 0; fn < 19; ++fn) {
        int col = wn * 304 + fn * 16 + l16;
        float bv = bcat[col];
#pragma unroll
        for (int i = 0; i < 4; ++i) {
            int row = wm * 16 + g16 * 4 + i;
            float v = acc[fn][i] + bv;
            if (col < 599)       spS[row][col] = (bf16)v;
            else if (col == 599) abS[row][0] = v;
            else if (col == 600) abS[row][1] = v;
        }
    }
    __syncthreads();

    // ================= spline phase: wave wid -> rows wid*8..wid*8+7 =========
    const bool act = lane < 50;
    const float EC = 0.53974247f;                 // log(exp(0.999)-1)

    auto rng = [](float x) -> int {               // first j with tau_j >= x
        int v = (int)ceilf(fmaf(200.f, x, -0.5f));
        return v < 0 ? 0 : (v > 200 ? 200 : v);
    };

#pragma unroll 1
    for (int it = 0; it < 8; ++it) {
        const int r = wid * 8 + it;
        const bf16* spr = &spS[r][0];
        const float sa = __expf(abS[r][0]);
        const float sb = abS[r][1];

        // ---- W logits: softmax -> per-lane inclusive partials -> wave scan ----
        float p0, p1, p2, p3;
        {
            float x0, x1, x2v, x3;
            if (act) {
                bf16x4 v = *(const bf16x4*)&spr[4 * lane];
                x0 = (float)v[0]; x1 = (float)v[1]; x2v = (float)v[2]; x3 = (float)v[3];
            } else { x0 = x1 = x2v = x3 = -1e30f; }
            float m = fmaxf(fmaxf(x0, x1), fmaxf(x2v, x3));
#pragma unroll
            for (int d = 1; d < 64; d <<= 1) m = fmaxf(m, __shfl_xor(m, d));
            float e0 = act ? __expf(x0 - m) : 0.f;
            float e1 = act ? __expf(x1 - m) : 0.f;
            float e2 = act ? __expf(x2v - m) : 0.f;
            float e3 = act ? __expf(x3 - m) : 0.f;
            float s = e0 + e1 + e2 + e3;
#pragma unroll
            for (int d = 1; d < 64; d <<= 1) s += __shfl_xor(s, d);
            float inv = 0.8f / s;
            p0 = act ? fmaf(e0, inv, 0.001f) : 0.f;
            p1 = act ? fmaf(e1, inv, 0.001f) : 0.f;
            p2 = act ? fmaf(e2, inv, 0.001f) : 0.f;
            p3 = act ? fmaf(e3, inv, 0.001f) : 0.f;
        }
        float c0 = p0, c1 = c0 + p1, c2 = c1 + p2, c3 = c2 + p3;
        float run = c3, ts = run;
#pragma unroll
        for (int d = 1; d < 64; d <<= 1) { float u = __shfl_up(ts, d); if (lane >= d) ts += u; }
        float excl  = ts - run;
        float nexcl = __shfl_down(excl, 1);
        float cwl0 = excl, cwl1 = excl + c0, cwl2 = excl + c1, cwl3 = excl + c2;
        float cwr3 = (lane == 49) ? 1.0f : nexcl;     // cw[:, -1].set(1.0)

        // ---- H logits ----
        float hp0, hp1, hp2, hp3;
        {
            float x0, x1, x2v, x3;
            if (act) {
                bf16x4 v = *(const bf16x4*)&spr[200 + 4 * lane];
                x0 = (float)v[0]; x1 = (float)v[1]; x2v = (float)v[2]; x3 = (float)v[3];
            } else { x0 = x1 = x2v = x3 = -1e30f; }
            float m = fmaxf(fmaxf(x0, x1), fmaxf(x2v, x3));
#pragma unroll
            for (int d = 1; d < 64; d <<= 1) m = fmaxf(m, __shfl_xor(m, d));
            float e0 = act ? __expf(x0 - m) : 0.f;
            float e1 = act ? __expf(x1 - m) : 0.f;
            float e2 = act ? __expf(x2v - m) : 0.f;
            float e3 = act ? __expf(x3 - m) : 0.f;
            float s = e0 + e1 + e2 + e3;
#pragma unroll
            for (int d = 1; d < 64; d <<= 1) s += __shfl_xor(s, d);
            float inv = 0.8f / s;
            hp0 = act ? fmaf(e0, inv, 0.001f) : 0.f;
            hp1 = act ? fmaf(e1, inv, 0.001f) : 0.f;
            hp2 = act ? fmaf(e2, inv, 0.001f) : 0.f;
            hp3 = act ? fmaf(e3, inv, 0.001f) : 0.f;
        }
        float hc0 = hp0, hc1 = hc0 + hp1, hc2 = hc1 + hp2, hc3 = hc2 + hp3;
        float hrun = hc3, hts = hrun;
#pragma unroll
        for (int d = 1; d < 64; d <<= 1) { float u = __shfl_up(hts, d); if (lane >= d) hts += u; }
        float hexcl  = hts - hrun;
        float nhexcl = __shfl_down(hexcl, 1);
        float ch0 = fmaf(sa, hexcl, sb);
        float ch1 = fmaf(sa, hexcl + hc0, sb);
        float ch2 = fmaf(sa, hexcl + hc1, sb);
        float ch3 = fmaf(sa, hexcl + hc2, sb);
        float chr3 = fmaf(sa, nhexcl, sb);            // = ch[4*lane+4]

        // ---- D: softplus of Dp; dd[e] per owned bin via one shfl ----
        float dv0, dv1, dv2, dv3;
        {
            float x0 = 0.f, x1 = 0.f, x2v = 0.f, x3 = 0.f;
            if (act) {
                bf16x4 v = *(const bf16x4*)&spr[400 + 4 * lane];
                x0 = (float)v[0]; x1 = (float)v[1]; x2v = (float)v[2]; x3 = (float)v[3];
            }
            auto spls = [](float x) {
                return fmaxf(x, 0.f) + __logf(1.f + __expf(-fabsf(x))) + 0.001f;
            };
            dv0 = spls(x0); dv1 = spls(x1); dv2 = spls(x2v); dv3 = spls(x3);
        }
        if (lane == 49) dv3 = EC;                     // dd[200] = EDGE (slot holds 'a' junk)
        float dprev = __shfl_up(dv3, 1);              // dd[4*lane] from prev lane
        if (lane == 0) dprev = EC;                    // dd[0] = EDGE

        // ---- output ranges (exact partition via shared boundary floats) ----
        int b0 = rng(cwl0), b1 = rng(cwl1), b2 = rng(cwl2), b3 = rng(cwl3);
        int b4 = (lane == 49) ? 200 : rng(nexcl);

        if (act) {
            float* orow = out + (size_t)(row0 + r) * 200;
            auto emit = [&](int lo, int hi, float wl, float wr_, float hl, float hr,
                            float d0, float d1) {
                float w = wr_ - wl;
                float h = hr - hl;
                float invw = 1.f / w;
                float delta = h * invw;
                float dd2 = d0 + d1 - 2.f * delta;
                for (int jj = lo; jj < hi; ++jj) {
                    float tau = ((float)jj + 0.5f) * (1.f / 200.f);
                    float th = (tau - wl) * invw;
                    float t1 = th * (1.f - th);
                    float numer = h * (delta * th * th + d0 * t1);
                    float denom = fmaf(dd2, t1, delta);
                    orow[jj] = hl + numer / denom;
                }
            };
            emit(b0, b1, cwl0, cwl1, ch0, ch1, dprev, dv0);
            emit(b1, b2, cwl1, cwl2, ch1, ch2, dv0,   dv1);
            emit(b2, b3, cwl2, cwl3, ch2, ch3, dv1,   dv2);
            emit(b3, b4, cwl3, cwr3, ch3, chr3, dv2,  dv3);
        }
    }
}

// ---------------------------------------------------------------------------
// Host launcher
// ---------------------------------------------------------------------------
extern "C" void kernel_launch(void* const* d_in, const int* in_sizes, int n_in,
                              void* d_out, int out_size, void* d_ws, size_t ws_size,
                              hipStream_t stream)
{
    const float* inputs = (const float*)d_in[0];
    const float* W1  = (const float*)d_in[1];
    const float* b1  = (const float*)d_in[2];
    const float* g1  = (const float*)d_in[3];
    const float* be1 = (const float*)d_in[4];
    const float* W2  = (const float*)d_in[5];
    const float* b2  = (const float*)d_in[6];
    const float* g2  = (const float*)d_in[7];
    const float* be2 = (const float*)d_in[8];
    const float* WV  = (const float*)d_in[9];
    const float* bV  = (const float*)d_in[10];
    const float* Wa  = (const float*)d_in[11];
    const float* ba  = (const float*)d_in[12];
    const float* Wb  = (const float*)d_in[13];
    const float* bb  = (const float*)d_in[14];
    float* out = (float*)d_out;

    char* ws = (char*)d_ws;
    bf16*  w1b  = (bf16*) (ws + 0);          //   131072
    bf16*  w2b  = (bf16*) (ws + 131072);     //   524288
    bf16*  wcat = (bf16*) (ws + 655360);     //   622592
    float* bcat = (float*)(ws + 1277952);    //     4096 (608 used)
    bf16*  x2   = (bf16*) (ws + 1282048);    // 67108864 (B x 512)

    const int preptot = 512 * 128 + 512 * 512 + NCAT * 512 + NCAT;
    prep_kernel<<<(preptot + 255) / 256, 256, 0, stream>>>(
        W1, W2, WV, bV, Wa, ba, Wb, bb, w1b, w2b, wcat, bcat);

    fused_mlp<<<BATCH / 64, 512, 0, stream>>>(
        inputs, w1b, b1, g1, be1, w2b, b2, g2, be2, x2);

    gemm_spline<<<BATCH / 64, 512, 0, stream>>>(x2, wcat, bcat, out);
}

// Round 3
// 263.456 us; speedup vs baseline: 1.6456x; 1.6456x over previous
//
#include <hip/hip_runtime.h>
#include <stdint.h>

typedef __bf16 bf16;
typedef __bf16 bf16x8 __attribute__((ext_vector_type(8)));
typedef __bf16 bf16x4 __attribute__((ext_vector_type(4)));
typedef float  f32x4  __attribute__((ext_vector_type(4)));
typedef uint32_t u32;

#define BATCH    65536
#define NCAT     640      // 599 spline logits + a + b, padded to 640 (40 frags)
#define SPSTRIDE 604      // sp row stride in elements (keeps ws under proven cap)

// async global->LDS, 16B per lane; LDS dest = wave-uniform base + lane*16
__device__ __forceinline__ void async16(const void* g, void* l) {
    __builtin_amdgcn_global_load_lds(
        (const u32 __attribute__((address_space(1)))*)g,
        (u32 __attribute__((address_space(3)))*)l,
        16, 0, 0);
}

// ---------------------------------------------------------------------------
// Kernel 0: cast weights to bf16; assemble Wcat[640][512] = [WV; Wa; Wb; 0]
// ---------------------------------------------------------------------------
__global__ __launch_bounds__(256) void prep_kernel(
    const float* W1, const float* W2, const float* WV,
    const float* bV, const float* Wa, const float* ba,
    const float* Wb, const float* bb,
    bf16* w1b, bf16* w2b, bf16* wcat, float* bcat)
{
    int idx = blockIdx.x * 256 + threadIdx.x;
    const int n1 = 512 * 128, n2 = 512 * 512, n3 = NCAT * 512;
    if (idx < n1) { w1b[idx] = (bf16)W1[idx]; return; }
    idx -= n1;
    if (idx < n2) { w2b[idx] = (bf16)W2[idx]; return; }
    idx -= n2;
    if (idx < n3) {
        int n = idx >> 9, k = idx & 511;
        float v = 0.f;
        if (n < 599)       v = WV[n * 512 + k];
        else if (n == 599) v = Wa[k];
        else if (n == 600) v = Wb[k];
        wcat[idx] = (bf16)v;
        return;
    }
    idx -= n3;
    if (idx < NCAT) {
        float v = 0.f;
        if (idx < 599)       v = bV[idx];
        else if (idx == 599) v = ba[0];
        else if (idx == 600) v = bb[0];
        bcat[idx] = v;
    }
}

// ---------------------------------------------------------------------------
// G1/G2: C[64 x 512] = A[64 x K] @ W[512 x K]^T + b -> LN -> ReLU -> bf16
// 8 waves 2Mx4N, wave tile 32x128. Double-buffered LDS, global_load_lds 16B.
// AF32: A is f32 (inputs); staged as f32 with within-row XOR swizzle
// (128B rows would otherwise be a 16-way bank conflict), converted on read.
// ---------------------------------------------------------------------------
template <int KDIM, bool AF32>
__global__ __launch_bounds__(512, 4) void gemm_ln(
    const void* Av, const bf16* __restrict__ W,
    const float* __restrict__ bias, const float* __restrict__ gamma,
    const float* __restrict__ beta, bf16* out)
{
    constexpr int ABUF = AF32 ? 8192 : 4096;      // one A buffer, bytes
    __shared__ __align__(16) char smem[2 * ABUF + 65536];
    char* Abase = smem;
    char* Bbase = smem + 2 * ABUF;

    const int t = threadIdx.x;
    const int lane = t & 63, wid = t >> 6;
    const int wm = wid >> 2, wn = wid & 3;
    const int l16 = lane & 15, g16 = lane >> 4;
    const long row0 = (long)blockIdx.x * 64;

    constexpr int NT = KDIM / 32;

    f32x4 acc[2][8];
#pragma unroll
    for (int a = 0; a < 2; ++a)
#pragma unroll
        for (int b = 0; b < 8; ++b) acc[a][b] = (f32x4){0.f, 0.f, 0.f, 0.f};

    auto stageA = [&](int kt, int bi) {
        const int k0 = kt * 32;
        if (AF32) {                      // 8 calls of 1KB: wave wid does call wid
            int row = wid * 8 + (lane >> 3);
            int colf = ((lane & 7) * 4) ^ (((lane >> 3) & 7) << 2);   // pre-swizzled src
            const float* src = (const float*)Av + (row0 + row) * KDIM + k0 + colf;
            async16(src, Abase + bi * ABUF + wid * 1024);
        } else {                         // 4 calls: waves 0..3
            if (wid < 4) {
                int row = wid * 16 + (lane >> 2);
                const bf16* src = (const bf16*)Av + (row0 + row) * (long)KDIM + k0 + (lane & 3) * 8;
                async16(src, Abase + bi * ABUF + wid * 1024);
            }
        }
    };
    auto stageB = [&](int kt, int bi) {  // 32 calls of 1KB: 4 per wave
        const int k0 = kt * 32;
#pragma unroll
        for (int c = 0; c < 4; ++c) {
            int call = wid * 4 + c;
            int row = call * 16 + (lane >> 2);
            const bf16* src = W + (long)row * KDIM + k0 + (lane & 3) * 8;
            async16(src, Bbase + bi * 32768 + call * 1024);
        }
    };

    stageA(0, 0); stageB(0, 0);
    __syncthreads();

    for (int kt = 0; kt < NT; ++kt) {
        const int bi = kt & 1;
        if (kt + 1 < NT) { stageA(kt + 1, bi ^ 1); stageB(kt + 1, bi ^ 1); }

        bf16x8 af[2];
        if (AF32) {
            const float* Af = (const float*)(Abase + bi * ABUF);
#pragma unroll
            for (int fm = 0; fm < 2; ++fm) {
                int r = wm * 32 + fm * 16 + l16;
                int m8 = (r & 7) << 2;
                f32x4 v0 = *(const f32x4*)(Af + r * 32 + ((g16 * 8)     ^ m8));
                f32x4 v1 = *(const f32x4*)(Af + r * 32 + ((g16 * 8 + 4) ^ m8));
                bf16x8 h;
                h[0]=(bf16)v0[0]; h[1]=(bf16)v0[1]; h[2]=(bf16)v0[2]; h[3]=(bf16)v0[3];
                h[4]=(bf16)v1[0]; h[5]=(bf16)v1[1]; h[6]=(bf16)v1[2]; h[7]=(bf16)v1[3];
                af[fm] = h;
            }
        } else {
            const bf16* Ab = (const bf16*)(Abase + bi * ABUF);
#pragma unroll
            for (int fm = 0; fm < 2; ++fm)
                af[fm] = *(const bf16x8*)(Ab + (wm * 32 + fm * 16 + l16) * 32 + g16 * 8);
        }
        const bf16* Bb = (const bf16*)(Bbase + bi * 32768);
#pragma unroll
        for (int fn = 0; fn < 8; ++fn) {
            bf16x8 bv = *(const bf16x8*)(Bb + (wn * 128 + fn * 16 + l16) * 32 + g16 * 8);
            acc[0][fn] = __builtin_amdgcn_mfma_f32_16x16x32_bf16(af[0], bv, acc[0][fn], 0, 0, 0);
            acc[1][fn] = __builtin_amdgcn_mfma_f32_16x16x32_bf16(af[1], bv, acc[1][fn], 0, 0, 0);
        }
        __syncthreads();    // drains staged loads (vmcnt) + all waves done with bi
    }

    // ---- epilogue: +bias, LN over 512, ReLU, bf16 store. P aliases A bufs ----
    float* Psum = (float*)Abase;            // 64*4 f32
    float* Psq  = (float*)(Abase + 1024);
#pragma unroll
    for (int fm = 0; fm < 2; ++fm)
#pragma unroll
        for (int fn = 0; fn < 8; ++fn) {
            float bv = bias[wn * 128 + fn * 16 + l16];
#pragma unroll
            for (int i = 0; i < 4; ++i) acc[fm][fn][i] += bv;
        }
#pragma unroll
    for (int fm = 0; fm < 2; ++fm)
#pragma unroll
        for (int i = 0; i < 4; ++i) {
            float s = 0.f, q = 0.f;
#pragma unroll
            for (int fn = 0; fn < 8; ++fn) { float v = acc[fm][fn][i]; s += v; q += v * v; }
#pragma unroll
            for (int m = 1; m < 16; m <<= 1) { s += __shfl_xor(s, m); q += __shfl_xor(q, m); }
            if (l16 == 0) {
                int lr = wm * 32 + fm * 16 + g16 * 4 + i;
                Psum[lr * 4 + wn] = s; Psq[lr * 4 + wn] = q;
            }
        }
    __syncthreads();
#pragma unroll
    for (int fm = 0; fm < 2; ++fm)
#pragma unroll
        for (int i = 0; i < 4; ++i) {
            int lr = wm * 32 + fm * 16 + g16 * 4 + i;
            float s = Psum[lr * 4 + 0] + Psum[lr * 4 + 1] + Psum[lr * 4 + 2] + Psum[lr * 4 + 3];
            float q = Psq[lr * 4 + 0] + Psq[lr * 4 + 1] + Psq[lr * 4 + 2] + Psq[lr * 4 + 3];
            float mean = s * (1.f / 512.f);
            float var  = q * (1.f / 512.f) - mean * mean;
            float rstd = rsqrtf(var + 1e-5f);
            long grow = row0 + lr;
#pragma unroll
            for (int fn = 0; fn < 8; ++fn) {
                int col = wn * 128 + fn * 16 + l16;
                float o = (acc[fm][fn][i] - mean) * rstd * gamma[col] + beta[col];
                out[grow * 512 + col] = (bf16)fmaxf(o, 0.f);
            }
        }
}

// ---------------------------------------------------------------------------
// G3: sp[128 x 640] = X2[128 x 512] @ Wcat[640 x 512]^T + bcat
// 8 waves 2Mx4N, wave tile 64x160 (acc[4][10]); dbuf + global_load_lds.
// cols<599 -> sp bf16 (stride 604); col 599/600 -> ab f32.
// ---------------------------------------------------------------------------
__global__ __launch_bounds__(512, 2) void gemm_cat(
    const bf16* __restrict__ A, const bf16* __restrict__ W,
    const float* __restrict__ bcat, bf16* __restrict__ sp, float* __restrict__ ab)
{
    __shared__ __align__(16) char smem[16384 + 81920];   // A 2x8K, B 2x40K
    char* Abase = smem;
    char* Bbase = smem + 16384;

    const int t = threadIdx.x;
    const int lane = t & 63, wid = t >> 6;
    const int wm = wid >> 2, wn = wid & 3;
    const int l16 = lane & 15, g16 = lane >> 4;
    const long row0 = (long)blockIdx.x * 128;

    f32x4 acc[4][10];
#pragma unroll
    for (int a = 0; a < 4; ++a)
#pragma unroll
        for (int b = 0; b < 10; ++b) acc[a][b] = (f32x4){0.f, 0.f, 0.f, 0.f};

    auto stageA = [&](int kt, int bi) {     // 8 calls: one per wave
        int row = wid * 16 + (lane >> 2);
        const bf16* src = A + (row0 + row) * 512 + kt * 32 + (lane & 3) * 8;
        async16(src, Abase + bi * 8192 + wid * 1024);
    };
    auto stageB = [&](int kt, int bi) {     // 40 calls: 5 per wave
#pragma unroll
        for (int c = 0; c < 5; ++c) {
            int call = wid * 5 + c;
            int row = call * 16 + (lane >> 2);
            const bf16* src = W + (long)row * 512 + kt * 32 + (lane & 3) * 8;
            async16(src, Bbase + bi * 40960 + call * 1024);
        }
    };

    stageA(0, 0); stageB(0, 0);
    __syncthreads();

    for (int kt = 0; kt < 16; ++kt) {
        const int bi = kt & 1;
        if (kt < 15) { stageA(kt + 1, bi ^ 1); stageB(kt + 1, bi ^ 1); }
        const bf16* Ab = (const bf16*)(Abase + bi * 8192);
        const bf16* Bb = (const bf16*)(Bbase + bi * 40960);
        bf16x8 af[4];
#pragma unroll
        for (int fm = 0; fm < 4; ++fm)
            af[fm] = *(const bf16x8*)(Ab + (wm * 64 + fm * 16 + l16) * 32 + g16 * 8);
#pragma unroll
        for (int fn = 0; fn < 10; ++fn) {
            bf16x8 bv = *(const bf16x8*)(Bb + (wn * 160 + fn * 16 + l16) * 32 + g16 * 8);
#pragma unroll
            for (int fm = 0; fm < 4; ++fm)
                acc[fm][fn] = __builtin_amdgcn_mfma_f32_16x16x32_bf16(af[fm], bv, acc[fm][fn], 0, 0, 0);
        }
        __syncthreads();
    }

#pragma unroll
    for (int fn = 0; fn < 10; ++fn) {
        int col = wn * 160 + fn * 16 + l16;
        float bv = (col <= 600) ? bcat[col] : 0.f;
#pragma unroll
        for (int fm = 0; fm < 4; ++fm)
#pragma unroll
            for (int i = 0; i < 4; ++i) {
                long grow = row0 + wm * 64 + fm * 16 + g16 * 4 + i;
                float v = acc[fm][fn][i] + bv;
                if (col < 599)       sp[grow * SPSTRIDE + col] = (bf16)v;
                else if (col == 599) ab[grow * 2 + 0] = v;
                else if (col == 600) ab[grow * 2 + 1] = v;
            }
    }
}

// ---------------------------------------------------------------------------
// Spline: LDS-free, register/shuffle-only. One wave per row, 4 rows/block.
// Each lane owns 4 bins (params in regs after wave scans); outputs emitted by
// scatter over the owned-bin tau range (exact partition, no search).
// ---------------------------------------------------------------------------
__global__ __launch_bounds__(256) void spline_kernel(
    const bf16* __restrict__ sp, const float* __restrict__ ab, float* __restrict__ out)
{
    const int t = threadIdx.x;
    const int lane = t & 63, wid = t >> 6;
    const long row = (long)blockIdx.x * 4 + wid;
    const bf16* spr = sp + row * SPSTRIDE;
    const bool act = lane < 50;
    const float EC = 0.53974247f;                 // log(exp(0.999)-1)

    const float sa = __expf(ab[row * 2 + 0]);
    const float sb = ab[row * 2 + 1];

    auto rng = [](float x) -> int {               // first j with tau_j >= x
        int v = (int)ceilf(fmaf(200.f, x, -0.5f));
        return v < 0 ? 0 : (v > 200 ? 200 : v);
    };

    // ---- W logits -> widths -> cw ----
    float p0, p1, p2, p3;
    {
        float x0, x1, x2v, x3;
        if (act) {
            bf16x4 v = *(const bf16x4*)&spr[4 * lane];
            x0 = (float)v[0]; x1 = (float)v[1]; x2v = (float)v[2]; x3 = (float)v[3];
        } else { x0 = x1 = x2v = x3 = -1e30f; }
        float m = fmaxf(fmaxf(x0, x1), fmaxf(x2v, x3));
#pragma unroll
        for (int d = 1; d < 64; d <<= 1) m = fmaxf(m, __shfl_xor(m, d));
        float e0 = act ? __expf(x0 - m) : 0.f;
        float e1 = act ? __expf(x1 - m) : 0.f;
        float e2 = act ? __expf(x2v - m) : 0.f;
        float e3 = act ? __expf(x3 - m) : 0.f;
        float s = e0 + e1 + e2 + e3;
#pragma unroll
        for (int d = 1; d < 64; d <<= 1) s += __shfl_xor(s, d);
        float inv = 0.8f / s;
        p0 = act ? fmaf(e0, inv, 0.001f) : 0.f;
        p1 = act ? fmaf(e1, inv, 0.001f) : 0.f;
        p2 = act ? fmaf(e2, inv, 0.001f) : 0.f;
        p3 = act ? fmaf(e3, inv, 0.001f) : 0.f;
    }
    float c0 = p0, c1 = c0 + p1, c2 = c1 + p2, c3 = c2 + p3;
    float run = c3, ts = run;
#pragma unroll
    for (int d = 1; d < 64; d <<= 1) { float u = __shfl_up(ts, d); if (lane >= d) ts += u; }
    float excl  = ts - run;
    float nexcl = __shfl_down(excl, 1);
    float cwl0 = excl, cwl1 = excl + c0, cwl2 = excl + c1, cwl3 = excl + c2;
    float cwr3 = (lane == 49) ? 1.0f : nexcl;     // cw[:, -1].set(1.0)

    // ---- H logits -> heights -> ch ----
    float hp0, hp1, hp2, hp3;
    {
        float x0, x1, x2v, x3;
        if (act) {
            bf16x4 v = *(const bf16x4*)&spr[200 + 4 * lane];
            x0 = (float)v[0]; x1 = (float)v[1]; x2v = (float)v[2]; x3 = (float)v[3];
        } else { x0 = x1 = x2v = x3 = -1e30f; }
        float m = fmaxf(fmaxf(x0, x1), fmaxf(x2v, x3));
#pragma unroll
        for (int d = 1; d < 64; d <<= 1) m = fmaxf(m, __shfl_xor(m, d));
        float e0 = act ? __expf(x0 - m) : 0.f;
        float e1 = act ? __expf(x1 - m) : 0.f;
        float e2 = act ? __expf(x2v - m) : 0.f;
        float e3 = act ? __expf(x3 - m) : 0.f;
        float s = e0 + e1 + e2 + e3;
#pragma unroll
        for (int d = 1; d < 64; d <<= 1) s += __shfl_xor(s, d);
        float inv = 0.8f / s;
        hp0 = act ? fmaf(e0, inv, 0.001f) : 0.f;
        hp1 = act ? fmaf(e1, inv, 0.001f) : 0.f;
        hp2 = act ? fmaf(e2, inv, 0.001f) : 0.f;
        hp3 = act ? fmaf(e3, inv, 0.001f) : 0.f;
    }
    float hc0 = hp0, hc1 = hc0 + hp1, hc2 = hc1 + hp2, hc3 = hc2 + hp3;
    float hrun = hc3, hts = hrun;
#pragma unroll
    for (int d = 1; d < 64; d <<= 1) { float u = __shfl_up(hts, d); if (lane >= d) hts += u; }
    float hexcl  = hts - hrun;
    float nhexcl = __shfl_down(hexcl, 1);
    float ch0 = fmaf(sa, hexcl, sb);
    float ch1 = fmaf(sa, hexcl + hc0, sb);
    float ch2 = fmaf(sa, hexcl + hc1, sb);
    float ch3 = fmaf(sa, hexcl + hc2, sb);
    float chr3 = fmaf(sa, nhexcl, sb);            // ch[4*lane+4]

    // ---- D (softplus), edges via shfl ----
    float dv0, dv1, dv2, dv3;
    {
        float x0 = 0.f, x1 = 0.f, x2v = 0.f, x3 = 0.f;
        if (act) {
            bf16x4 v = *(const bf16x4*)&spr[400 + 4 * lane];
            x0 = (float)v[0]; x1 = (float)v[1]; x2v = (float)v[2]; x3 = (float)v[3];
        }
        auto spls = [](float x) {
            return fmaxf(x, 0.f) + __logf(1.f + __expf(-fabsf(x))) + 0.001f;
        };
        dv0 = spls(x0); dv1 = spls(x1); dv2 = spls(x2v); dv3 = spls(x3);
    }
    if (lane == 49) dv3 = EC;                     // dd[200] = EDGE
    float dprev = __shfl_up(dv3, 1);
    if (lane == 0) dprev = EC;                    // dd[0] = EDGE

    int b0 = rng(cwl0), b1 = rng(cwl1), b2 = rng(cwl2), b3 = rng(cwl3);
    int b4 = (lane == 49) ? 200 : rng(nexcl);

    if (act) {
        float* orow = out + (size_t)row * 200;
        auto emit = [&](int lo, int hi, float wl, float wr_, float hl, float hr,
                        float d0, float d1) {
            float w = wr_ - wl;
            float h = hr - hl;
            float invw = 1.f / w;
            float delta = h * invw;
            float dd2 = d0 + d1 - 2.f * delta;
            for (int jj = lo; jj < hi; ++jj) {
                float tau = ((float)jj + 0.5f) * (1.f / 200.f);
                float th = (tau - wl) * invw;
                float t1 = th * (1.f - th);
                float numer = h * (delta * th * th + d0 * t1);
                float denom = fmaf(dd2, t1, delta);
                orow[jj] = hl + numer / denom;
            }
        };
        emit(b0, b1, cwl0, cwl1, ch0, ch1, dprev, dv0);
        emit(b1, b2, cwl1, cwl2, ch1, ch2, dv0,   dv1);
        emit(b2, b3, cwl2, cwl3, ch2, ch3, dv1,   dv2);
        emit(b3, b4, cwl3, cwr3, ch3, chr3, dv2,  dv3);
    }
}

// ---------------------------------------------------------------------------
// Host launcher
// ---------------------------------------------------------------------------
extern "C" void kernel_launch(void* const* d_in, const int* in_sizes, int n_in,
                              void* d_out, int out_size, void* d_ws, size_t ws_size,
                              hipStream_t stream)
{
    const float* inputs = (const float*)d_in[0];
    const float* W1  = (const float*)d_in[1];
    const float* b1  = (const float*)d_in[2];
    const float* g1  = (const float*)d_in[3];
    const float* be1 = (const float*)d_in[4];
    const float* W2  = (const float*)d_in[5];
    const float* b2  = (const float*)d_in[6];
    const float* g2  = (const float*)d_in[7];
    const float* be2 = (const float*)d_in[8];
    const float* WV  = (const float*)d_in[9];
    const float* bV  = (const float*)d_in[10];
    const float* Wa  = (const float*)d_in[11];
    const float* ba  = (const float*)d_in[12];
    const float* Wb  = (const float*)d_in[13];
    const float* bb  = (const float*)d_in[14];
    float* out = (float*)d_out;

    char* ws = (char*)d_ws;
    bf16*  w1b  = (bf16*) (ws + 0);          //   131072
    bf16*  w2b  = (bf16*) (ws + 131072);     //   524288
    bf16*  wcat = (bf16*) (ws + 655360);     //   655360 (640x512)
    float* bcat = (float*)(ws + 1310720);    //     2560
    float* ab   = (float*)(ws + 1313280);    //   524288 (B x 2)
    bf16*  x    = (bf16*) (ws + 2097152);    // 67108864 (B x 512, L1->L2 in place)
    bf16*  spb  = (bf16*) (ws + 69206016);   // 79167488 (B x 604) -> ends 148373504

    const int preptot = 512 * 128 + 512 * 512 + NCAT * 512 + NCAT;
    prep_kernel<<<(preptot + 255) / 256, 256, 0, stream>>>(
        W1, W2, WV, bV, Wa, ba, Wb, bb, w1b, w2b, wcat, bcat);

    gemm_ln<128, true ><<<BATCH / 64, 512, 0, stream>>>(inputs, w1b, b1, g1, be1, x);
    gemm_ln<512, false><<<BATCH / 64, 512, 0, stream>>>(x,      w2b, b2, g2, be2, x);
    gemm_cat<<<BATCH / 128, 512, 0, stream>>>(x, wcat, bcat, spb, ab);
    spline_kernel<<<BATCH / 4, 256, 0, stream>>>(spb, ab, out);
}

// Round 4
// 258.471 us; speedup vs baseline: 1.6774x; 1.0193x over previous
//
#include <hip/hip_runtime.h>
#include <stdint.h>

typedef __bf16 bf16;
typedef __bf16 bf16x8 __attribute__((ext_vector_type(8)));
typedef __bf16 bf16x4 __attribute__((ext_vector_type(4)));
typedef float  f32x4  __attribute__((ext_vector_type(4)));
typedef uint32_t u32;

#define BATCH    65536
#define NCAT     640      // 599 spline logits + a + b, padded to 640
#define SPSTRIDE 604      // sp row stride in elements

// async global->LDS, 16B per lane; LDS dest = wave-uniform base + lane*16
__device__ __forceinline__ void async16(const void* g, void* l) {
    __builtin_amdgcn_global_load_lds(
        (const u32 __attribute__((address_space(1)))*)g,
        (u32 __attribute__((address_space(3)))*)l,
        16, 0, 0);
}

// ---------------------------------------------------------------------------
// Kernel 0: weights -> bf16; Wcat[640][512] = [WV; Wa; Wb; 0]; inputs -> bf16
// ---------------------------------------------------------------------------
__global__ __launch_bounds__(256) void prep_kernel(
    const float* W1, const float* W2, const float* WV,
    const float* bV, const float* Wa, const float* ba,
    const float* Wb, const float* bb, const float* inputs,
    bf16* w1b, bf16* w2b, bf16* wcat, float* bcat, bf16* xin)
{
    int idx = blockIdx.x * 256 + threadIdx.x;
    const int n1 = 512 * 128, n2 = 512 * 512, n3 = NCAT * 512;
    const int n5 = BATCH * 128 / 8;                 // 8 floats per item
    if (idx < n5) {                                  // input cast (bulk) first
        const float4* src = (const float4*)(inputs + idx * 8);
        float4 v0 = src[0], v1 = src[1];
        bf16x8 h;
        h[0]=(bf16)v0.x; h[1]=(bf16)v0.y; h[2]=(bf16)v0.z; h[3]=(bf16)v0.w;
        h[4]=(bf16)v1.x; h[5]=(bf16)v1.y; h[6]=(bf16)v1.z; h[7]=(bf16)v1.w;
        *(bf16x8*)&xin[idx * 8] = h;
        return;
    }
    idx -= n5;
    if (idx < n1) { w1b[idx] = (bf16)W1[idx]; return; }
    idx -= n1;
    if (idx < n2) { w2b[idx] = (bf16)W2[idx]; return; }
    idx -= n2;
    if (idx < n3) {
        int n = idx >> 9, k = idx & 511;
        float v = 0.f;
        if (n < 599)       v = WV[n * 512 + k];
        else if (n == 599) v = Wa[k];
        else if (n == 600) v = Wb[k];
        wcat[idx] = (bf16)v;
        return;
    }
    idx -= n3;
    if (idx < NCAT) {
        float v = 0.f;
        if (idx < 599)       v = bV[idx];
        else if (idx == 599) v = ba[0];
        else if (idx == 600) v = bb[0];
        bcat[idx] = v;
    }
}

// ---------------------------------------------------------------------------
// G1/G2: C[64 x 512] = A[64 x K] @ W[512 x K]^T + b -> LN -> ReLU -> bf16
// 8 waves 2Mx4N, wave tile 32x128. Double-buffered LDS, global_load_lds 16B.
// ---------------------------------------------------------------------------
template <int KDIM>
__global__ __launch_bounds__(512, 4) void gemm_ln(
    const bf16* __restrict__ A, const bf16* __restrict__ W,
    const float* __restrict__ bias, const float* __restrict__ gamma,
    const float* __restrict__ beta, bf16* out)
{
    __shared__ __align__(16) char smem[8192 + 65536];   // A 2x4K, B 2x32K
    char* Abase = smem;
    char* Bbase = smem + 8192;

    const int t = threadIdx.x;
    const int lane = t & 63, wid = t >> 6;
    const int wm = wid >> 2, wn = wid & 3;
    const int l16 = lane & 15, g16 = lane >> 4;
    const long row0 = (long)blockIdx.x * 64;
    constexpr int NT = KDIM / 32;

    f32x4 acc[2][8];
#pragma unroll
    for (int a = 0; a < 2; ++a)
#pragma unroll
        for (int b = 0; b < 8; ++b) acc[a][b] = (f32x4){0.f, 0.f, 0.f, 0.f};

    auto stageA = [&](int kt, int bi) {     // 4 calls: waves 0..3
        if (wid < 4) {
            int row = wid * 16 + (lane >> 2);
            const bf16* src = A + (row0 + row) * (long)KDIM + kt * 32 + (lane & 3) * 8;
            async16(src, Abase + bi * 4096 + wid * 1024);
        }
    };
    auto stageB = [&](int kt, int bi) {     // 32 calls: 4 per wave
#pragma unroll
        for (int c = 0; c < 4; ++c) {
            int call = wid * 4 + c;
            int row = call * 16 + (lane >> 2);
            const bf16* src = W + (long)row * KDIM + kt * 32 + (lane & 3) * 8;
            async16(src, Bbase + bi * 32768 + call * 1024);
        }
    };

    stageA(0, 0); stageB(0, 0);
    __syncthreads();

    for (int kt = 0; kt < NT; ++kt) {
        const int bi = kt & 1;
        if (kt + 1 < NT) { stageA(kt + 1, bi ^ 1); stageB(kt + 1, bi ^ 1); }
        const bf16* Ab = (const bf16*)(Abase + bi * 4096);
        const bf16* Bb = (const bf16*)(Bbase + bi * 32768);
        bf16x8 af[2];
#pragma unroll
        for (int fm = 0; fm < 2; ++fm)
            af[fm] = *(const bf16x8*)(Ab + (wm * 32 + fm * 16 + l16) * 32 + g16 * 8);
#pragma unroll
        for (int fn = 0; fn < 8; ++fn) {
            bf16x8 bv = *(const bf16x8*)(Bb + (wn * 128 + fn * 16 + l16) * 32 + g16 * 8);
            acc[0][fn] = __builtin_amdgcn_mfma_f32_16x16x32_bf16(af[0], bv, acc[0][fn], 0, 0, 0);
            acc[1][fn] = __builtin_amdgcn_mfma_f32_16x16x32_bf16(af[1], bv, acc[1][fn], 0, 0, 0);
        }
        __syncthreads();
    }

    // ---- epilogue: +bias, LN over 512, ReLU, bf16 store ----
    float* Psum = (float*)Abase;
    float* Psq  = (float*)(Abase + 1024);
#pragma unroll
    for (int fm = 0; fm < 2; ++fm)
#pragma unroll
        for (int fn = 0; fn < 8; ++fn) {
            float bv = bias[wn * 128 + fn * 16 + l16];
#pragma unroll
            for (int i = 0; i < 4; ++i) acc[fm][fn][i] += bv;
        }
#pragma unroll
    for (int fm = 0; fm < 2; ++fm)
#pragma unroll
        for (int i = 0; i < 4; ++i) {
            float s = 0.f, q = 0.f;
#pragma unroll
            for (int fn = 0; fn < 8; ++fn) { float v = acc[fm][fn][i]; s += v; q += v * v; }
#pragma unroll
            for (int m = 1; m < 16; m <<= 1) { s += __shfl_xor(s, m); q += __shfl_xor(q, m); }
            if (l16 == 0) {
                int lr = wm * 32 + fm * 16 + g16 * 4 + i;
                Psum[lr * 4 + wn] = s; Psq[lr * 4 + wn] = q;
            }
        }
    __syncthreads();
#pragma unroll
    for (int fm = 0; fm < 2; ++fm)
#pragma unroll
        for (int i = 0; i < 4; ++i) {
            int lr = wm * 32 + fm * 16 + g16 * 4 + i;
            float s = Psum[lr * 4 + 0] + Psum[lr * 4 + 1] + Psum[lr * 4 + 2] + Psum[lr * 4 + 3];
            float q = Psq[lr * 4 + 0] + Psq[lr * 4 + 1] + Psq[lr * 4 + 2] + Psq[lr * 4 + 3];
            float mean = s * (1.f / 512.f);
            float var  = q * (1.f / 512.f) - mean * mean;
            float rstd = rsqrtf(var + 1e-5f);
            long grow = row0 + lr;
#pragma unroll
            for (int fn = 0; fn < 8; ++fn) {
                int col = wn * 128 + fn * 16 + l16;
                float o = (acc[fm][fn][i] - mean) * rstd * gamma[col] + beta[col];
                out[grow * 512 + col] = (bf16)fmaxf(o, 0.f);
            }
        }
}

// ---------------------------------------------------------------------------
// G3: sp[128 x 320-half] = X2[128 x 512] @ Wcat^T + bcat
// grid = (BATCH/128) x 2 N-halves; 8 waves 2Mx4N, wave tile 64x80 (acc[4][5]).
// LDS 56KB -> 2 blocks/CU. cols<599 -> sp bf16; col 599/600 -> ab f32.
// ---------------------------------------------------------------------------
__global__ __launch_bounds__(512, 4) void gemm_cat(
    const bf16* __restrict__ A, const bf16* __restrict__ W,
    const float* __restrict__ bcat, bf16* __restrict__ sp, float* __restrict__ ab)
{
    __shared__ __align__(16) char smem[16384 + 40960];   // A 2x8K, B 2x20K
    char* Abase = smem;
    char* Bbase = smem + 16384;

    const int t = threadIdx.x;
    const int lane = t & 63, wid = t >> 6;
    const int wm = wid >> 2, wn = wid & 3;
    const int l16 = lane & 15, g16 = lane >> 4;
    const int nh  = blockIdx.x & 1;                  // N-half: cols [320nh, 320nh+320)
    const long row0 = (long)(blockIdx.x >> 1) * 128;

    f32x4 acc[4][5];
#pragma unroll
    for (int a = 0; a < 4; ++a)
#pragma unroll
        for (int b = 0; b < 5; ++b) acc[a][b] = (f32x4){0.f, 0.f, 0.f, 0.f};

    auto stageA = [&](int kt, int bi) {     // 8 calls: one per wave
        int row = wid * 16 + (lane >> 2);
        const bf16* src = A + (row0 + row) * 512 + kt * 32 + (lane & 3) * 8;
        async16(src, Abase + bi * 8192 + wid * 1024);
    };
    auto stageB = [&](int kt, int bi) {     // 20 calls
#pragma unroll
        for (int c = 0; c < 3; ++c) {
            int call = c * 8 + wid;
            if (call < 20) {
                int row = nh * 320 + call * 16 + (lane >> 2);
                const bf16* src = W + (long)row * 512 + kt * 32 + (lane & 3) * 8;
                async16(src, Bbase + bi * 20480 + call * 1024);
            }
        }
    };

    stageA(0, 0); stageB(0, 0);
    __syncthreads();

    for (int kt = 0; kt < 16; ++kt) {
        const int bi = kt & 1;
        if (kt < 15) { stageA(kt + 1, bi ^ 1); stageB(kt + 1, bi ^ 1); }
        const bf16* Ab = (const bf16*)(Abase + bi * 8192);
        const bf16* Bb = (const bf16*)(Bbase + bi * 20480);
        bf16x8 af[4];
#pragma unroll
        for (int fm = 0; fm < 4; ++fm)
            af[fm] = *(const bf16x8*)(Ab + (wm * 64 + fm * 16 + l16) * 32 + g16 * 8);
#pragma unroll
        for (int fn = 0; fn < 5; ++fn) {
            bf16x8 bv = *(const bf16x8*)(Bb + (wn * 80 + fn * 16 + l16) * 32 + g16 * 8);
#pragma unroll
            for (int fm = 0; fm < 4; ++fm)
                acc[fm][fn] = __builtin_amdgcn_mfma_f32_16x16x32_bf16(af[fm], bv, acc[fm][fn], 0, 0, 0);
        }
        __syncthreads();
    }

#pragma unroll
    for (int fn = 0; fn < 5; ++fn) {
        int col = nh * 320 + wn * 80 + fn * 16 + l16;
        float bv = (col <= 600) ? bcat[col] : 0.f;
#pragma unroll
        for (int fm = 0; fm < 4; ++fm)
#pragma unroll
            for (int i = 0; i < 4; ++i) {
                long grow = row0 + wm * 64 + fm * 16 + g16 * 4 + i;
                float v = acc[fm][fn][i] + bv;
                if (col < 599)       sp[grow * SPSTRIDE + col] = (bf16)v;
                else if (col == 599) ab[grow * 2 + 0] = v;
                else if (col == 600) ab[grow * 2 + 1] = v;
            }
    }
}

// ---------------------------------------------------------------------------
// Spline v3: register scan -> LDS param tables (aligned b128 stores) ->
// binidx scatter (1-store body) -> balanced gather: lane computes exactly
// 4 outputs j = lane + 50k (consecutive lanes -> consecutive LDS addrs).
// ---------------------------------------------------------------------------
__global__ __launch_bounds__(256) void spline_kernel(
    const bf16* __restrict__ sp, const float* __restrict__ ab, float* __restrict__ out)
{
    __shared__ float S[4][816];     // per wave: cw@0, ch@204, dd@408, binidx@612
    const int t = threadIdx.x;
    const int lane = t & 63, wid = t >> 6;
    const long row = (long)blockIdx.x * 4 + wid;
    const bf16* spr = sp + row * SPSTRIDE;
    const bool act = lane < 50;
    const float EC = 0.53974247f;                 // log(exp(0.999)-1)
    float* cw = &S[wid][0];
    float* ch = &S[wid][204];
    float* dd = &S[wid][408];
    int*   bx = (int*)&S[wid][612];

    const float sa = __expf(ab[row * 2 + 0]);
    const float sb = ab[row * 2 + 1];

    auto rng = [](float x) -> int {               // first j with tau_j >= x
        int v = (int)ceilf(fmaf(200.f, x, -0.5f));
        return v < 0 ? 0 : (v > 200 ? 200 : v);
    };

    // ---- W logits -> widths -> cw[4l..4l+3] in regs ----
    float p0, p1, p2, p3;
    {
        float x0, x1, x2v, x3;
        if (act) {
            bf16x4 v = *(const bf16x4*)&spr[4 * lane];
            x0 = (float)v[0]; x1 = (float)v[1]; x2v = (float)v[2]; x3 = (float)v[3];
        } else { x0 = x1 = x2v = x3 = -1e30f; }
        float m = fmaxf(fmaxf(x0, x1), fmaxf(x2v, x3));
#pragma unroll
        for (int d = 1; d < 64; d <<= 1) m = fmaxf(m, __shfl_xor(m, d));
        float e0 = act ? __expf(x0 - m) : 0.f;
        float e1 = act ? __expf(x1 - m) : 0.f;
        float e2 = act ? __expf(x2v - m) : 0.f;
        float e3 = act ? __expf(x3 - m) : 0.f;
        float s = e0 + e1 + e2 + e3;
#pragma unroll
        for (int d = 1; d < 64; d <<= 1) s += __shfl_xor(s, d);
        float inv = 0.8f / s;
        p0 = act ? fmaf(e0, inv, 0.001f) : 0.f;
        p1 = act ? fmaf(e1, inv, 0.001f) : 0.f;
        p2 = act ? fmaf(e2, inv, 0.001f) : 0.f;
        p3 = act ? fmaf(e3, inv, 0.001f) : 0.f;
    }
    float c0 = p0, c1 = c0 + p1, c2 = c1 + p2, c3 = c2 + p3;
    float run = c3, ts = run;
#pragma unroll
    for (int d = 1; d < 64; d <<= 1) { float u = __shfl_up(ts, d); if (lane >= d) ts += u; }
    float excl  = ts - run;
    float nexcl = __shfl_down(excl, 1);
    float cwl0 = excl, cwl1 = excl + c0, cwl2 = excl + c1, cwl3 = excl + c2;

    // ---- H logits -> heights -> ch[4l..4l+3] ----
    float hp0, hp1, hp2, hp3;
    {
        float x0, x1, x2v, x3;
        if (act) {
            bf16x4 v = *(const bf16x4*)&spr[200 + 4 * lane];
            x0 = (float)v[0]; x1 = (float)v[1]; x2v = (float)v[2]; x3 = (float)v[3];
        } else { x0 = x1 = x2v = x3 = -1e30f; }
        float m = fmaxf(fmaxf(x0, x1), fmaxf(x2v, x3));
#pragma unroll
        for (int d = 1; d < 64; d <<= 1) m = fmaxf(m, __shfl_xor(m, d));
        float e0 = act ? __expf(x0 - m) : 0.f;
        float e1 = act ? __expf(x1 - m) : 0.f;
        float e2 = act ? __expf(x2v - m) : 0.f;
        float e3 = act ? __expf(x3 - m) : 0.f;
        float s = e0 + e1 + e2 + e3;
#pragma unroll
        for (int d = 1; d < 64; d <<= 1) s += __shfl_xor(s, d);
        float inv = 0.8f / s;
        hp0 = act ? fmaf(e0, inv, 0.001f) : 0.f;
        hp1 = act ? fmaf(e1, inv, 0.001f) : 0.f;
        hp2 = act ? fmaf(e2, inv, 0.001f) : 0.f;
        hp3 = act ? fmaf(e3, inv, 0.001f) : 0.f;
    }
    float hc0 = hp0, hc1 = hc0 + hp1, hc2 = hc1 + hp2, hc3 = hc2 + hp3;
    float hrun = hc3, hts = hrun;
#pragma unroll
    for (int d = 1; d < 64; d <<= 1) { float u = __shfl_up(hts, d); if (lane >= d) hts += u; }
    float hexcl = hts - hrun;
    float ch0 = fmaf(sa, hexcl, sb);
    float ch1 = fmaf(sa, hexcl + hc0, sb);
    float ch2 = fmaf(sa, hexcl + hc1, sb);
    float ch3 = fmaf(sa, hexcl + hc2, sb);

    // ---- D (softplus): dd[4l..4l+3] = {dprev, dv0, dv1, dv2} ----
    float dv0, dv1, dv2, dv3;
    {
        float x0 = 0.f, x1 = 0.f, x2v = 0.f, x3 = 0.f;
        if (act) {
            bf16x4 v = *(const bf16x4*)&spr[400 + 4 * lane];
            x0 = (float)v[0]; x1 = (float)v[1]; x2v = (float)v[2]; x3 = (float)v[3];
        }
        auto spls = [](float x) {
            return fmaxf(x, 0.f) + __logf(1.f + __expf(-fabsf(x))) + 0.001f;
        };
        dv0 = spls(x0); dv1 = spls(x1); dv2 = spls(x2v); dv3 = spls(x3);
    }
    if (lane == 49) dv3 = EC;                     // dd[200] = EDGE
    float dprev = __shfl_up(dv3, 1);
    if (lane == 0) dprev = EC;                    // dd[0] = EDGE

    // ---- write param tables (aligned 16B stores) + tails ----
    if (act) {
        *(f32x4*)&cw[4 * lane] = (f32x4){cwl0, cwl1, cwl2, cwl3};
        *(f32x4*)&ch[4 * lane] = (f32x4){ch0, ch1, ch2, ch3};
        *(f32x4*)&dd[4 * lane] = (f32x4){dprev, dv0, dv1, dv2};
    }
    if (lane == 49) {
        cw[200] = 1.0f;                           // cw[:, -1].set(1.0)
        ch[200] = fmaf(sa, hts, sb);              // sa * total + sb
        dd[200] = EC;
    }

    // ---- scatter bin indices (tiny body; exact partition of [0,200)) ----
    if (act) {
        int b0 = rng(cwl0), b1 = rng(cwl1), b2 = rng(cwl2), b3 = rng(cwl3);
        int b4 = (lane == 49) ? 200 : rng(nexcl);
        for (int j = b0; j < b1; ++j) bx[j] = 4 * lane;
        for (int j = b1; j < b2; ++j) bx[j] = 4 * lane + 1;
        for (int j = b2; j < b3; ++j) bx[j] = 4 * lane + 2;
        for (int j = b3; j < b4; ++j) bx[j] = 4 * lane + 3;
    }
    asm volatile("s_waitcnt lgkmcnt(0)" ::: "memory");   // same-wave LDS RAW

    // ---- balanced gather: lane -> outputs j = lane + 50k ----
    if (act) {
        float* orow = out + (size_t)row * 200;
#pragma unroll
        for (int k = 0; k < 4; ++k) {
            int j = lane + 50 * k;
            int b = bx[j];
            float wl = cw[b], wr = cw[b + 1];
            float hl = ch[b], hr = ch[b + 1];
            float d0 = dd[b], d1 = dd[b + 1];
            float tau = ((float)j + 0.5f) * (1.f / 200.f);
            float w = wr - wl, h = hr - hl;
            float invw = 1.f / w;
            float delta = h * invw;
            float th = (tau - wl) * invw;
            float t1 = th * (1.f - th);
            float numer = h * fmaf(delta * th, th, d0 * t1);
            float denom = fmaf(d0 + d1 - 2.f * delta, t1, delta);
            orow[j] = hl + numer / denom;
        }
    }
}

// ---------------------------------------------------------------------------
// Host launcher
// ---------------------------------------------------------------------------
extern "C" void kernel_launch(void* const* d_in, const int* in_sizes, int n_in,
                              void* d_out, int out_size, void* d_ws, size_t ws_size,
                              hipStream_t stream)
{
    const float* inputs = (const float*)d_in[0];
    const float* W1  = (const float*)d_in[1];
    const float* b1  = (const float*)d_in[2];
    const float* g1  = (const float*)d_in[3];
    const float* be1 = (const float*)d_in[4];
    const float* W2  = (const float*)d_in[5];
    const float* b2  = (const float*)d_in[6];
    const float* g2  = (const float*)d_in[7];
    const float* be2 = (const float*)d_in[8];
    const float* WV  = (const float*)d_in[9];
    const float* bV  = (const float*)d_in[10];
    const float* Wa  = (const float*)d_in[11];
    const float* ba  = (const float*)d_in[12];
    const float* Wb  = (const float*)d_in[13];
    const float* bb  = (const float*)d_in[14];
    float* out = (float*)d_out;

    char* ws = (char*)d_ws;
    bf16*  w1b  = (bf16*) (ws + 0);          //   131072
    bf16*  w2b  = (bf16*) (ws + 131072);     //   524288
    bf16*  wcat = (bf16*) (ws + 655360);     //   655360 (640x512)
    float* bcat = (float*)(ws + 1310720);    //     2560
    float* ab   = (float*)(ws + 1313280);    //   524288 (B x 2)
    bf16*  x    = (bf16*) (ws + 2097152);    // 67108864 (B x 512, L1->L2 in place)
    bf16*  spb  = (bf16*) (ws + 69206016);   // 79167488 (B x 604)
    bf16*  xin  = (bf16*) (ws + 69206016);   // 16777216 (B x 128) — dead before G3 writes spb

    const int preptot = BATCH * 128 / 8 + 512 * 128 + 512 * 512 + NCAT * 512 + NCAT;
    prep_kernel<<<(preptot + 255) / 256, 256, 0, stream>>>(
        W1, W2, WV, bV, Wa, ba, Wb, bb, inputs, w1b, w2b, wcat, bcat, xin);

    gemm_ln<128><<<BATCH / 64, 512, 0, stream>>>(xin, w1b, b1, g1, be1, x);
    gemm_ln<512><<<BATCH / 64, 512, 0, stream>>>(x,   w2b, b2, g2, be2, x);
    gemm_cat<<<(BATCH / 128) * 2, 512, 0, stream>>>(x, wcat, bcat, spb, ab);
    spline_kernel<<<BATCH / 4, 256, 0, stream>>>(spb, ab, out);
}

// Round 5
// 250.124 us; speedup vs baseline: 1.7333x; 1.0334x over previous
//
#include <hip/hip_runtime.h>
#include <stdint.h>

typedef __bf16 bf16;
typedef __bf16 bf16x8 __attribute__((ext_vector_type(8)));
typedef __bf16 bf16x4 __attribute__((ext_vector_type(4)));
typedef float  f32x4  __attribute__((ext_vector_type(4)));
typedef uint32_t u32;

#define BATCH    65536
#define NCAT     640      // 599 spline logits + a + b, padded to 640
#define SPSTRIDE 604      // sp row stride in elements

// async global->LDS, 16B per lane; LDS dest = wave-uniform base + lane*16
__device__ __forceinline__ void async16(const void* g, void* l) {
    __builtin_amdgcn_global_load_lds(
        (const u32 __attribute__((address_space(1)))*)g,
        (u32 __attribute__((address_space(3)))*)l,
        16, 0, 0);
}

// ---------------------------------------------------------------------------
// Kernel 0: weights -> bf16; Wcat[640][512] = [WV; Wa; Wb; 0]; inputs -> bf16
// ---------------------------------------------------------------------------
__global__ __launch_bounds__(256) void prep_kernel(
    const float* W1, const float* W2, const float* WV,
    const float* bV, const float* Wa, const float* ba,
    const float* Wb, const float* bb, const float* inputs,
    bf16* w1b, bf16* w2b, bf16* wcat, float* bcat, bf16* xin)
{
    int idx = blockIdx.x * 256 + threadIdx.x;
    const int n1 = 512 * 128, n2 = 512 * 512, n3 = NCAT * 512;
    const int n5 = BATCH * 128 / 8;                 // 8 floats per item
    if (idx < n5) {                                  // input cast (bulk) first
        const float4* src = (const float4*)(inputs + idx * 8);
        float4 v0 = src[0], v1 = src[1];
        bf16x8 h;
        h[0]=(bf16)v0.x; h[1]=(bf16)v0.y; h[2]=(bf16)v0.z; h[3]=(bf16)v0.w;
        h[4]=(bf16)v1.x; h[5]=(bf16)v1.y; h[6]=(bf16)v1.z; h[7]=(bf16)v1.w;
        *(bf16x8*)&xin[idx * 8] = h;
        return;
    }
    idx -= n5;
    if (idx < n1) { w1b[idx] = (bf16)W1[idx]; return; }
    idx -= n1;
    if (idx < n2) { w2b[idx] = (bf16)W2[idx]; return; }
    idx -= n2;
    if (idx < n3) {
        int n = idx >> 9, k = idx & 511;
        float v = 0.f;
        if (n < 599)       v = WV[n * 512 + k];
        else if (n == 599) v = Wa[k];
        else if (n == 600) v = Wb[k];
        wcat[idx] = (bf16)v;
        return;
    }
    idx -= n3;
    if (idx < NCAT) {
        float v = 0.f;
        if (idx < 599)       v = bV[idx];
        else if (idx == 599) v = ba[0];
        else if (idx == 600) v = bb[0];
        bcat[idx] = v;
    }
}

// ---------------------------------------------------------------------------
// G1/G2: C[64 x 512] = A[64 x K] @ W[512 x K]^T + b -> LN -> ReLU -> bf16
// 8 waves 2Mx4N, wave tile 32x128. Dbuf LDS + global_load_lds 16B.
// Output staged in LDS (aliases B bufs) -> dense 16B-aligned global stores.
// ---------------------------------------------------------------------------
template <int KDIM>
__global__ __launch_bounds__(512, 4) void gemm_ln(
    const bf16* __restrict__ A, const bf16* __restrict__ W,
    const float* __restrict__ bias, const float* __restrict__ gamma,
    const float* __restrict__ beta, bf16* out)
{
    __shared__ __align__(16) char smem[8192 + 65536];   // A 2x4K, B 2x32K
    char* Abase = smem;
    char* Bbase = smem + 8192;

    const int t = threadIdx.x;
    const int lane = t & 63, wid = t >> 6;
    const int wm = wid >> 2, wn = wid & 3;
    const int l16 = lane & 15, g16 = lane >> 4;
    const long row0 = (long)blockIdx.x * 64;
    constexpr int NT = KDIM / 32;

    f32x4 acc[2][8];
#pragma unroll
    for (int a = 0; a < 2; ++a)
#pragma unroll
        for (int b = 0; b < 8; ++b) acc[a][b] = (f32x4){0.f, 0.f, 0.f, 0.f};

    auto stageA = [&](int kt, int bi) {     // 4 calls: waves 0..3
        if (wid < 4) {
            int row = wid * 16 + (lane >> 2);
            const bf16* src = A + (row0 + row) * (long)KDIM + kt * 32 + (lane & 3) * 8;
            async16(src, Abase + bi * 4096 + wid * 1024);
        }
    };
    auto stageB = [&](int kt, int bi) {     // 32 calls: 4 per wave
#pragma unroll
        for (int c = 0; c < 4; ++c) {
            int call = wid * 4 + c;
            int row = call * 16 + (lane >> 2);
            const bf16* src = W + (long)row * KDIM + kt * 32 + (lane & 3) * 8;
            async16(src, Bbase + bi * 32768 + call * 1024);
        }
    };

    stageA(0, 0); stageB(0, 0);
    __syncthreads();

    for (int kt = 0; kt < NT; ++kt) {
        const int bi = kt & 1;
        if (kt + 1 < NT) { stageA(kt + 1, bi ^ 1); stageB(kt + 1, bi ^ 1); }
        const bf16* Ab = (const bf16*)(Abase + bi * 4096);
        const bf16* Bb = (const bf16*)(Bbase + bi * 32768);
        bf16x8 af[2];
#pragma unroll
        for (int fm = 0; fm < 2; ++fm)
            af[fm] = *(const bf16x8*)(Ab + (wm * 32 + fm * 16 + l16) * 32 + g16 * 8);
#pragma unroll
        for (int fn = 0; fn < 8; ++fn) {
            bf16x8 bv = *(const bf16x8*)(Bb + (wn * 128 + fn * 16 + l16) * 32 + g16 * 8);
            acc[0][fn] = __builtin_amdgcn_mfma_f32_16x16x32_bf16(af[0], bv, acc[0][fn], 0, 0, 0);
            acc[1][fn] = __builtin_amdgcn_mfma_f32_16x16x32_bf16(af[1], bv, acc[1][fn], 0, 0, 0);
        }
        __syncthreads();
    }

    // ---- epilogue: +bias, LN over 512, ReLU -> LDS stage -> dense store ----
    float* Psum = (float*)Abase;                  // 64x4 f32
    float* Psq  = (float*)(Abase + 1024);
    bf16*  stg  = (bf16*)Bbase;                   // 64x512 bf16 = 64KB
#pragma unroll
    for (int fm = 0; fm < 2; ++fm)
#pragma unroll
        for (int fn = 0; fn < 8; ++fn) {
            float bv = bias[wn * 128 + fn * 16 + l16];
#pragma unroll
            for (int i = 0; i < 4; ++i) acc[fm][fn][i] += bv;
        }
#pragma unroll
    for (int fm = 0; fm < 2; ++fm)
#pragma unroll
        for (int i = 0; i < 4; ++i) {
            float s = 0.f, q = 0.f;
#pragma unroll
            for (int fn = 0; fn < 8; ++fn) { float v = acc[fm][fn][i]; s += v; q += v * v; }
#pragma unroll
            for (int m = 1; m < 16; m <<= 1) { s += __shfl_xor(s, m); q += __shfl_xor(q, m); }
            if (l16 == 0) {
                int lr = wm * 32 + fm * 16 + g16 * 4 + i;
                Psum[lr * 4 + wn] = s; Psq[lr * 4 + wn] = q;
            }
        }
    __syncthreads();
#pragma unroll
    for (int fm = 0; fm < 2; ++fm)
#pragma unroll
        for (int i = 0; i < 4; ++i) {
            int lr = wm * 32 + fm * 16 + g16 * 4 + i;
            float s = Psum[lr * 4 + 0] + Psum[lr * 4 + 1] + Psum[lr * 4 + 2] + Psum[lr * 4 + 3];
            float q = Psq[lr * 4 + 0] + Psq[lr * 4 + 1] + Psq[lr * 4 + 2] + Psq[lr * 4 + 3];
            float mean = s * (1.f / 512.f);
            float var  = q * (1.f / 512.f) - mean * mean;
            float rstd = rsqrtf(var + 1e-5f);
#pragma unroll
            for (int fn = 0; fn < 8; ++fn) {
                int col = wn * 128 + fn * 16 + l16;
                float o = (acc[fm][fn][i] - mean) * rstd * gamma[col] + beta[col];
                stg[lr * 512 + col] = (bf16)fmaxf(o, 0.f);
            }
        }
    __syncthreads();
#pragma unroll
    for (int i = 0; i < 8; ++i) {                 // 64 rows x 1KB, dense
        int idx = i * 512 + t;
        *(bf16x8*)&out[(row0 + (idx >> 6)) * 512 + (idx & 63) * 8] =
            *(const bf16x8*)&stg[idx * 8];
    }
}

// ---------------------------------------------------------------------------
// G3: sp-half[64 x 320] = X2[64 x 512] @ Wcat^T + bcat
// grid = (BATCH/64) x 2 N-halves; 8 waves 2Mx4N, wave tile 32x80 (acc[2][5]).
// Output staged in LDS (aliases GEMM bufs) -> dense 8B-aligned stores.
// col 599/600 -> ab f32 straight from acc.
// ---------------------------------------------------------------------------
__global__ __launch_bounds__(512, 4) void gemm_cat(
    const bf16* __restrict__ A, const bf16* __restrict__ W,
    const float* __restrict__ bcat, bf16* __restrict__ sp, float* __restrict__ ab)
{
    __shared__ __align__(16) char smem[8192 + 40960];   // A 2x4K, B 2x20K
    char* Abase = smem;
    char* Bbase = smem + 8192;

    const int t = threadIdx.x;
    const int lane = t & 63, wid = t >> 6;
    const int wm = wid >> 2, wn = wid & 3;
    const int l16 = lane & 15, g16 = lane >> 4;
    const int nh  = blockIdx.x & 1;                  // N-half: cols [320nh, ..)
    const long row0 = (long)(blockIdx.x >> 1) * 64;

    f32x4 acc[2][5];
#pragma unroll
    for (int a = 0; a < 2; ++a)
#pragma unroll
        for (int b = 0; b < 5; ++b) acc[a][b] = (f32x4){0.f, 0.f, 0.f, 0.f};

    auto stageA = [&](int kt, int bi) {     // 4 calls: waves 0..3
        if (wid < 4) {
            int row = wid * 16 + (lane >> 2);
            const bf16* src = A + (row0 + row) * 512 + kt * 32 + (lane & 3) * 8;
            async16(src, Abase + bi * 4096 + wid * 1024);
        }
    };
    auto stageB = [&](int kt, int bi) {     // 20 calls
#pragma unroll
        for (int c = 0; c < 3; ++c) {
            int call = c * 8 + wid;
            if (call < 20) {
                int row = nh * 320 + call * 16 + (lane >> 2);
                const bf16* src = W + (long)row * 512 + kt * 32 + (lane & 3) * 8;
                async16(src, Bbase + bi * 20480 + call * 1024);
            }
        }
    };

    stageA(0, 0); stageB(0, 0);
    __syncthreads();

    for (int kt = 0; kt < 16; ++kt) {
        const int bi = kt & 1;
        if (kt < 15) { stageA(kt + 1, bi ^ 1); stageB(kt + 1, bi ^ 1); }
        const bf16* Ab = (const bf16*)(Abase + bi * 4096);
        const bf16* Bb = (const bf16*)(Bbase + bi * 20480);
        bf16x8 af[2];
#pragma unroll
        for (int fm = 0; fm < 2; ++fm)
            af[fm] = *(const bf16x8*)(Ab + (wm * 32 + fm * 16 + l16) * 32 + g16 * 8);
#pragma unroll
        for (int fn = 0; fn < 5; ++fn) {
            bf16x8 bv = *(const bf16x8*)(Bb + (wn * 80 + fn * 16 + l16) * 32 + g16 * 8);
            acc[0][fn] = __builtin_amdgcn_mfma_f32_16x16x32_bf16(af[0], bv, acc[0][fn], 0, 0, 0);
            acc[1][fn] = __builtin_amdgcn_mfma_f32_16x16x32_bf16(af[1], bv, acc[1][fn], 0, 0, 0);
        }
        __syncthreads();
    }

    // ---- epilogue: +bcat -> LDS stage [64][320]; ab f32 direct ----
    bf16* stg = (bf16*)smem;                      // 40KB, aliases GEMM bufs
#pragma unroll
    for (int fn = 0; fn < 5; ++fn) {
        int lcol = wn * 80 + fn * 16 + l16;
        int col  = nh * 320 + lcol;
        float bv = bcat[col];
#pragma unroll
        for (int fm = 0; fm < 2; ++fm)
#pragma unroll
            for (int i = 0; i < 4; ++i) {
                int r = wm * 32 + fm * 16 + g16 * 4 + i;
                float v = acc[fm][fn][i] + bv;
                stg[r * 320 + lcol] = (bf16)v;
                if (col == 599)      ab[(row0 + r) * 2 + 0] = v;
                else if (col == 600) ab[(row0 + r) * 2 + 1] = v;
            }
    }
    __syncthreads();
    // ---- dense writeout: nh=0 -> cols 0..319 (80 8B-chunks/row),
    //                      nh=1 -> cols 320..599 (70 8B-chunks/row) ----
    if (nh == 0) {
        for (int c = t; c < 64 * 80; c += 512) {
            int r = c / 80, k = c % 80;
            *(uint64_t*)&sp[(row0 + r) * SPSTRIDE + k * 4] =
                *(const uint64_t*)&stg[r * 320 + k * 4];
        }
    } else {
        for (int c = t; c < 64 * 70; c += 512) {
            int r = c / 70, k = c % 70;
            *(uint64_t*)&sp[(row0 + r) * SPSTRIDE + 320 + k * 4] =
                *(const uint64_t*)&stg[r * 320 + k * 4];
        }
    }
}

// ---------------------------------------------------------------------------
// Spline v3: register scan -> LDS param tables (aligned b128 stores) ->
// binidx scatter (1-store body) -> balanced gather: lane computes exactly
// 4 outputs j = lane + 50k.
// ---------------------------------------------------------------------------
__global__ __launch_bounds__(256) void spline_kernel(
    const bf16* __restrict__ sp, const float* __restrict__ ab, float* __restrict__ out)
{
    __shared__ float S[4][816];     // per wave: cw@0, ch@204, dd@408, binidx@612
    const int t = threadIdx.x;
    const int lane = t & 63, wid = t >> 6;
    const long row = (long)blockIdx.x * 4 + wid;
    const bf16* spr = sp + row * SPSTRIDE;
    const bool act = lane < 50;
    const float EC = 0.53974247f;                 // log(exp(0.999)-1)
    float* cw = &S[wid][0];
    float* ch = &S[wid][204];
    float* dd = &S[wid][408];
    int*   bx = (int*)&S[wid][612];

    const float sa = __expf(ab[row * 2 + 0]);
    const float sb = ab[row * 2 + 1];

    auto rng = [](float x) -> int {               // first j with tau_j >= x
        int v = (int)ceilf(fmaf(200.f, x, -0.5f));
        return v < 0 ? 0 : (v > 200 ? 200 : v);
    };

    // ---- W logits -> widths -> cw[4l..4l+3] in regs ----
    float p0, p1, p2, p3;
    {
        float x0, x1, x2v, x3;
        if (act) {
            bf16x4 v = *(const bf16x4*)&spr[4 * lane];
            x0 = (float)v[0]; x1 = (float)v[1]; x2v = (float)v[2]; x3 = (float)v[3];
        } else { x0 = x1 = x2v = x3 = -1e30f; }
        float m = fmaxf(fmaxf(x0, x1), fmaxf(x2v, x3));
#pragma unroll
        for (int d = 1; d < 64; d <<= 1) m = fmaxf(m, __shfl_xor(m, d));
        float e0 = act ? __expf(x0 - m) : 0.f;
        float e1 = act ? __expf(x1 - m) : 0.f;
        float e2 = act ? __expf(x2v - m) : 0.f;
        float e3 = act ? __expf(x3 - m) : 0.f;
        float s = e0 + e1 + e2 + e3;
#pragma unroll
        for (int d = 1; d < 64; d <<= 1) s += __shfl_xor(s, d);
        float inv = 0.8f / s;
        p0 = act ? fmaf(e0, inv, 0.001f) : 0.f;
        p1 = act ? fmaf(e1, inv, 0.001f) : 0.f;
        p2 = act ? fmaf(e2, inv, 0.001f) : 0.f;
        p3 = act ? fmaf(e3, inv, 0.001f) : 0.f;
    }
    float c0 = p0, c1 = c0 + p1, c2 = c1 + p2, c3 = c2 + p3;
    float run = c3, ts = run;
#pragma unroll
    for (int d = 1; d < 64; d <<= 1) { float u = __shfl_up(ts, d); if (lane >= d) ts += u; }
    float excl  = ts - run;
    float nexcl = __shfl_down(excl, 1);
    float cwl0 = excl, cwl1 = excl + c0, cwl2 = excl + c1, cwl3 = excl + c2;

    // ---- H logits -> heights -> ch[4l..4l+3] ----
    float hp0, hp1, hp2, hp3;
    {
        float x0, x1, x2v, x3;
        if (act) {
            bf16x4 v = *(const bf16x4*)&spr[200 + 4 * lane];
            x0 = (float)v[0]; x1 = (float)v[1]; x2v = (float)v[2]; x3 = (float)v[3];
        } else { x0 = x1 = x2v = x3 = -1e30f; }
        float m = fmaxf(fmaxf(x0, x1), fmaxf(x2v, x3));
#pragma unroll
        for (int d = 1; d < 64; d <<= 1) m = fmaxf(m, __shfl_xor(m, d));
        float e0 = act ? __expf(x0 - m) : 0.f;
        float e1 = act ? __expf(x1 - m) : 0.f;
        float e2 = act ? __expf(x2v - m) : 0.f;
        float e3 = act ? __expf(x3 - m) : 0.f;
        float s = e0 + e1 + e2 + e3;
#pragma unroll
        for (int d = 1; d < 64; d <<= 1) s += __shfl_xor(s, d);
        float inv = 0.8f / s;
        hp0 = act ? fmaf(e0, inv, 0.001f) : 0.f;
        hp1 = act ? fmaf(e1, inv, 0.001f) : 0.f;
        hp2 = act ? fmaf(e2, inv, 0.001f) : 0.f;
        hp3 = act ? fmaf(e3, inv, 0.001f) : 0.f;
    }
    float hc0 = hp0, hc1 = hc0 + hp1, hc2 = hc1 + hp2, hc3 = hc2 + hp3;
    float hrun = hc3, hts = hrun;
#pragma unroll
    for (int d = 1; d < 64; d <<= 1) { float u = __shfl_up(hts, d); if (lane >= d) hts += u; }
    float hexcl = hts - hrun;
    float ch0 = fmaf(sa, hexcl, sb);
    float ch1 = fmaf(sa, hexcl + hc0, sb);
    float ch2 = fmaf(sa, hexcl + hc1, sb);
    float ch3 = fmaf(sa, hexcl + hc2, sb);

    // ---- D (softplus): dd[4l..4l+3] = {dprev, dv0, dv1, dv2} ----
    float dv0, dv1, dv2, dv3;
    {
        float x0 = 0.f, x1 = 0.f, x2v = 0.f, x3 = 0.f;
        if (act) {
            bf16x4 v = *(const bf16x4*)&spr[400 + 4 * lane];
            x0 = (float)v[0]; x1 = (float)v[1]; x2v = (float)v[2]; x3 = (float)v[3];
        }
        auto spls = [](float x) {
            return fmaxf(x, 0.f) + __logf(1.f + __expf(-fabsf(x))) + 0.001f;
        };
        dv0 = spls(x0); dv1 = spls(x1); dv2 = spls(x2v); dv3 = spls(x3);
    }
    if (lane == 49) dv3 = EC;                     // dd[200] = EDGE
    float dprev = __shfl_up(dv3, 1);
    if (lane == 0) dprev = EC;                    // dd[0] = EDGE

    // ---- write param tables (aligned 16B stores) + tails ----
    if (act) {
        *(f32x4*)&cw[4 * lane] = (f32x4){cwl0, cwl1, cwl2, cwl3};
        *(f32x4*)&ch[4 * lane] = (f32x4){ch0, ch1, ch2, ch3};
        *(f32x4*)&dd[4 * lane] = (f32x4){dprev, dv0, dv1, dv2};
    }
    if (lane == 49) {
        cw[200] = 1.0f;                           // cw[:, -1].set(1.0)
        ch[200] = fmaf(sa, hts, sb);              // sa * total + sb
        dd[200] = EC;
    }

    // ---- scatter bin indices (tiny body; exact partition of [0,200)) ----
    if (act) {
        int b0 = rng(cwl0), b1 = rng(cwl1), b2 = rng(cwl2), b3 = rng(cwl3);
        int b4 = (lane == 49) ? 200 : rng(nexcl);
        for (int j = b0; j < b1; ++j) bx[j] = 4 * lane;
        for (int j = b1; j < b2; ++j) bx[j] = 4 * lane + 1;
        for (int j = b2; j < b3; ++j) bx[j] = 4 * lane + 2;
        for (int j = b3; j < b4; ++j) bx[j] = 4 * lane + 3;
    }
    asm volatile("s_waitcnt lgkmcnt(0)" ::: "memory");   // same-wave LDS RAW

    // ---- balanced gather: lane -> outputs j = lane + 50k ----
    if (act) {
        float* orow = out + (size_t)row * 200;
#pragma unroll
        for (int k = 0; k < 4; ++k) {
            int j = lane + 50 * k;
            int b = bx[j];
            float wl = cw[b], wr = cw[b + 1];
            float hl = ch[b], hr = ch[b + 1];
            float d0 = dd[b], d1 = dd[b + 1];
            float tau = ((float)j + 0.5f) * (1.f / 200.f);
            float w = wr - wl, h = hr - hl;
            float invw = 1.f / w;
            float delta = h * invw;
            float th = (tau - wl) * invw;
            float t1 = th * (1.f - th);
            float numer = h * fmaf(delta * th, th, d0 * t1);
            float denom = fmaf(d0 + d1 - 2.f * delta, t1, delta);
            orow[j] = hl + numer / denom;
        }
    }
}

// ---------------------------------------------------------------------------
// Host launcher
// ---------------------------------------------------------------------------
extern "C" void kernel_launch(void* const* d_in, const int* in_sizes, int n_in,
                              void* d_out, int out_size, void* d_ws, size_t ws_size,
                              hipStream_t stream)
{
    const float* inputs = (const float*)d_in[0];
    const float* W1  = (const float*)d_in[1];
    const float* b1  = (const float*)d_in[2];
    const float* g1  = (const float*)d_in[3];
    const float* be1 = (const float*)d_in[4];
    const float* W2  = (const float*)d_in[5];
    const float* b2  = (const float*)d_in[6];
    const float* g2  = (const float*)d_in[7];
    const float* be2 = (const float*)d_in[8];
    const float* WV  = (const float*)d_in[9];
    const float* bV  = (const float*)d_in[10];
    const float* Wa  = (const float*)d_in[11];
    const float* ba  = (const float*)d_in[12];
    const float* Wb  = (const float*)d_in[13];
    const float* bb  = (const float*)d_in[14];
    float* out = (float*)d_out;

    char* ws = (char*)d_ws;
    bf16*  w1b  = (bf16*) (ws + 0);          //   131072
    bf16*  w2b  = (bf16*) (ws + 131072);     //   524288
    bf16*  wcat = (bf16*) (ws + 655360);     //   655360 (640x512)
    float* bcat = (float*)(ws + 1310720);    //     2560 (640 f32)
    float* ab   = (float*)(ws + 1313280);    //   524288 (B x 2)
    bf16*  x    = (bf16*) (ws + 2097152);    // 67108864 (B x 512, L1->L2 in place)
    bf16*  spb  = (bf16*) (ws + 69206016);   // 79167488 (B x 604)
    bf16*  xin  = (bf16*) (ws + 69206016);   // 16777216 (B x 128) — dead before G3 writes spb

    const int preptot = BATCH * 128 / 8 + 512 * 128 + 512 * 512 + NCAT * 512 + NCAT;
    prep_kernel<<<(preptot + 255) / 256, 256, 0, stream>>>(
        W1, W2, WV, bV, Wa, ba, Wb, bb, inputs, w1b, w2b, wcat, bcat, xin);

    gemm_ln<128><<<BATCH / 64, 512, 0, stream>>>(xin, w1b, b1, g1, be1, x);
    gemm_ln<512><<<BATCH / 64, 512, 0, stream>>>(x,   w2b, b2, g2, be2, x);
    gemm_cat<<<(BATCH / 64) * 2, 512, 0, stream>>>(x, wcat, bcat, spb, ab);
    spline_kernel<<<BATCH / 4, 256, 0, stream>>>(spb, ab, out);
}